// Round 1
// baseline (1256.023 us; speedup 1.0000x reference)
//
#include <hip/hip_runtime.h>

#define N_NODES 100000
#define N_EDGES 3200000
#define F_INN 512
#define HIDD 16
#define NGR 256

// ---------------- degree ----------------
__global__ __launch_bounds__(256) void k_deg(const int* __restrict__ ei, float* __restrict__ deg) {
  int e = blockIdx.x * 256 + threadIdx.x;
  if (e < N_EDGES) {
    int dst = ei[N_EDGES + e];
    atomicAdd(&deg[dst], 1.0f);
  }
}

__global__ __launch_bounds__(256) void k_dinv(float* __restrict__ deg) {
  int i = blockIdx.x * 256 + threadIdx.x;
  if (i < N_NODES) deg[i] = rsqrtf(deg[i] + 1.0f);  // +1 for self loop
}

// ---------------- GEMM1: t1 = X @ W1 ; out1 = dinv^2 * t1 (self-loop init) ----------------
// block = 128 threads = 2 waves; each wave handles 64 rows (lane == row).
// X tile [64 rows][64 k] staged in LDS, stride 65 -> bank (lane+k)%32, 2-way (free).
// W k-tile [64][16] in LDS, read at uniform address (broadcast, conflict-free).
__global__ __launch_bounds__(128) void k_gemm1(const float* __restrict__ X,
                                               const float* __restrict__ W,
                                               const float* __restrict__ dinv,
                                               float* __restrict__ T1,
                                               float* __restrict__ O1) {
  __shared__ float Ws[64 * 16];        // 4 KB
  __shared__ float Xs[2][64 * 65];     // 33.3 KB
  const int wave = threadIdx.x >> 6;
  const int lane = threadIdx.x & 63;
  const int rowBase = blockIdx.x * 128 + wave * 64;
  const int myRow = rowBase + lane;

  float acc[16];
#pragma unroll
  for (int j = 0; j < 16; ++j) acc[j] = 0.f;

  for (int kt = 0; kt < F_INN; kt += 64) {
    // stage W tile: 1024 floats, 128 threads x 2 float4
    {
      int t = threadIdx.x;
      float4 w0 = *(const float4*)(W + kt * 16 + t * 8);
      float4 w1 = *(const float4*)(W + kt * 16 + t * 8 + 4);
      *(float4*)(&Ws[t * 8]) = w0;
      *(float4*)(&Ws[t * 8 + 4]) = w1;
    }
    // stage X tile: 64 rows x 64 cols per wave; 16 float4 per lane, coalesced
#pragma unroll
    for (int i = 0; i < 16; ++i) {
      int f = i * 64 + lane;          // 0..1023 float4 index
      int r = f >> 4;                 // row 0..63
      int kq = f & 15;                // float4 within row
      int gr = rowBase + r;
      float4 v = make_float4(0.f, 0.f, 0.f, 0.f);
      if (gr < N_NODES) v = *(const float4*)(X + (size_t)gr * F_INN + kt + kq * 4);
      float* p = &Xs[wave][r * 65 + kq * 4];
      p[0] = v.x; p[1] = v.y; p[2] = v.z; p[3] = v.w;   // b32 writes (pad 65)
    }
    __syncthreads();
#pragma unroll 8
    for (int k = 0; k < 64; ++k) {
      float xv = Xs[wave][lane * 65 + k];
#pragma unroll
      for (int j = 0; j < 16; ++j) acc[j] = fmaf(xv, Ws[k * 16 + j], acc[j]);
    }
    __syncthreads();
  }

  if (myRow < N_NODES) {
    float di = dinv[myRow];
    float w = di * di;
    float4* t = (float4*)(T1 + (size_t)myRow * 16);
    float4* o = (float4*)(O1 + (size_t)myRow * 16);
#pragma unroll
    for (int q = 0; q < 4; ++q) {
      float4 tv = make_float4(acc[q * 4 + 0], acc[q * 4 + 1], acc[q * 4 + 2], acc[q * 4 + 3]);
      t[q] = tv;
      o[q] = make_float4(w * tv.x, w * tv.y, w * tv.z, w * tv.w);
    }
  }
}

// ---------------- edge aggregation layer 1: out1[dst] += dinv[s]*dinv[d] * t1[src] ----------------
// 4 threads per edge (one float4 quarter each)
__global__ __launch_bounds__(256) void k_agg1(const int* __restrict__ ei,
                                              const float* __restrict__ dinv,
                                              const float* __restrict__ T1,
                                              float* __restrict__ O1) {
  int tt = blockIdx.x * 256 + threadIdx.x;
  int e = tt >> 2;
  int q = tt & 3;
  if (e < N_EDGES) {
    int s = ei[e];
    int d = ei[N_EDGES + e];
    float w = dinv[s] * dinv[d];
    float4 v = *(const float4*)(T1 + (size_t)s * 16 + q * 4);
    float* o = O1 + (size_t)d * 16 + q * 4;
    atomicAdd(o + 0, w * v.x);
    atomicAdd(o + 1, w * v.y);
    atomicAdd(o + 2, w * v.z);
    atomicAdd(o + 3, w * v.w);
  }
}

// ---------------- layer 2: h = relu(out1 + b1); t2 = h @ W2; out2 = dinv^2 * t2 ----------------
__global__ __launch_bounds__(256) void k_l2(const float* __restrict__ O1,
                                            const float* __restrict__ b1,
                                            const float* __restrict__ W2,
                                            const float* __restrict__ dinv,
                                            float* __restrict__ T2,
                                            float* __restrict__ O2) {
  int i = blockIdx.x * 256 + threadIdx.x;
  if (i >= N_NODES) return;
  const float4* r4 = (const float4*)(O1 + (size_t)i * 16);
  float h[16];
#pragma unroll
  for (int q = 0; q < 4; ++q) {
    float4 v = r4[q];
    h[q * 4 + 0] = v.x; h[q * 4 + 1] = v.y; h[q * 4 + 2] = v.z; h[q * 4 + 3] = v.w;
  }
  float a0 = 0.f, a1 = 0.f;
#pragma unroll
  for (int j = 0; j < 16; ++j) {
    float hv = fmaxf(h[j] + b1[j], 0.f);
    a0 = fmaf(hv, W2[j * 2 + 0], a0);
    a1 = fmaf(hv, W2[j * 2 + 1], a1);
  }
  float di = dinv[i];
  float w = di * di;
  T2[i * 2 + 0] = a0;
  T2[i * 2 + 1] = a1;
  O2[i * 2 + 0] = w * a0;
  O2[i * 2 + 1] = w * a1;
}

// ---------------- edge aggregation layer 2 ----------------
__global__ __launch_bounds__(256) void k_agg2(const int* __restrict__ ei,
                                              const float* __restrict__ dinv,
                                              const float* __restrict__ T2,
                                              float* __restrict__ O2) {
  int e = blockIdx.x * 256 + threadIdx.x;
  if (e < N_EDGES) {
    int s = ei[e];
    int d = ei[N_EDGES + e];
    float w = dinv[s] * dinv[d];
    float2 v = *(const float2*)(T2 + (size_t)s * 2);
    atomicAdd(&O2[(size_t)d * 2 + 0], w * v.x);
    atomicAdd(&O2[(size_t)d * 2 + 1], w * v.y);
  }
}

// ---------------- pooling: per-graph sums + counts (batch is sorted -> wave fast path) ----------------
__global__ __launch_bounds__(256) void k_pool(const float* __restrict__ O2,
                                              const int* __restrict__ batch,
                                              float* __restrict__ pool,
                                              float* __restrict__ cnt) {
  int i = blockIdx.x * 256 + threadIdx.x;
  bool valid = i < N_NODES;
  int b = valid ? batch[i] : -1;
  float vx = 0.f, vy = 0.f;
  if (valid) {
    vx = O2[(size_t)i * 2 + 0];
    vy = O2[(size_t)i * 2 + 1];
  }
  int b0 = __shfl(b, 0);
  if (__all(b == b0)) {
    if (b0 >= 0) {  // whole wave same (valid) graph: shuffle-reduce, 3 atomics total
#pragma unroll
      for (int o = 32; o > 0; o >>= 1) {
        vx += __shfl_xor(vx, o);
        vy += __shfl_xor(vy, o);
      }
      if ((threadIdx.x & 63) == 0) {
        atomicAdd(&pool[b0 * 2 + 0], vx);
        atomicAdd(&pool[b0 * 2 + 1], vy);
        atomicAdd(&cnt[b0], 64.0f);
      }
    }
  } else if (valid) {
    atomicAdd(&pool[b * 2 + 0], vx);
    atomicAdd(&pool[b * 2 + 1], vy);
    atomicAdd(&cnt[b], 1.0f);
  }
}

// ---------------- final: mean + b2 + log_softmax ----------------
__global__ __launch_bounds__(256) void k_final(const float* __restrict__ pool,
                                               const float* __restrict__ cnt,
                                               const float* __restrict__ b2,
                                               float* __restrict__ out) {
  int g = threadIdx.x;
  if (g < NGR) {
    float c = fmaxf(cnt[g], 1.0f);
    float p0 = pool[g * 2 + 0] / c + b2[0];
    float p1 = pool[g * 2 + 1] / c + b2[1];
    float m = fmaxf(p0, p1);
    float l = logf(expf(p0 - m) + expf(p1 - m));
    out[g * 2 + 0] = p0 - m - l;
    out[g * 2 + 1] = p1 - m - l;
  }
}

extern "C" void kernel_launch(void* const* d_in, const int* in_sizes, int n_in,
                              void* d_out, int out_size, void* d_ws, size_t ws_size,
                              hipStream_t stream) {
  const float* x  = (const float*)d_in[0];
  const float* W1 = (const float*)d_in[1];
  const float* b1 = (const float*)d_in[2];
  const float* W2 = (const float*)d_in[3];
  const float* b2 = (const float*)d_in[4];
  const int*   ei = (const int*)d_in[5];
  const int*   bt = (const int*)d_in[6];
  float* out = (float*)d_out;

  float* ws   = (float*)d_ws;
  float* deg  = ws;                       // N (becomes dinv in place)
  float* t1   = deg + N_NODES;            // N*16
  float* o1   = t1 + (size_t)N_NODES*16;  // N*16
  float* t2   = o1 + (size_t)N_NODES*16;  // N*2
  float* o2   = t2 + (size_t)N_NODES*2;   // N*2
  float* pool = o2 + (size_t)N_NODES*2;   // 512
  float* cnt  = pool + 2*NGR;             // 256

  const int NBN = (N_NODES + 255) / 256;  // 391

  hipMemsetAsync(deg, 0, (size_t)N_NODES * sizeof(float), stream);
  hipMemsetAsync(pool, 0, (size_t)(2*NGR + NGR) * sizeof(float), stream);

  k_deg<<<N_EDGES / 256, 256, 0, stream>>>(ei, deg);
  k_dinv<<<NBN, 256, 0, stream>>>(deg);
  k_gemm1<<<(N_NODES + 127) / 128, 128, 0, stream>>>(x, W1, deg, t1, o1);
  k_agg1<<<(N_EDGES * 4) / 256, 256, 0, stream>>>(ei, deg, t1, o1);
  k_l2<<<NBN, 256, 0, stream>>>(o1, b1, W2, deg, t2, o2);
  k_agg2<<<N_EDGES / 256, 256, 0, stream>>>(ei, deg, t2, o2);
  k_pool<<<NBN, 256, 0, stream>>>(o2, bt, pool, cnt);
  k_final<<<1, 256, 0, stream>>>(pool, cnt, b2, out);
}

// Round 2
// 535.948 us; speedup vs baseline: 2.3436x; 2.3436x over previous
//
#include <hip/hip_runtime.h>

#define N_NODES 100000
#define N_EDGES 3200000
#define F_INN 512
#define HIDD 16
#define NGR 256
#define NBN 391   // ceil(N_NODES/256)

// ---------------- in-degree count (int atomics, L2-resident) ----------------
__global__ __launch_bounds__(256) void k_deg(const int* __restrict__ ei, int* __restrict__ cnt) {
  int e = blockIdx.x * 256 + threadIdx.x;
  if (e < N_EDGES) atomicAdd(&cnt[ei[N_EDGES + e]], 1);
}

// ---------------- per-block exclusive scan of cnt + dinv ----------------
__global__ __launch_bounds__(256) void k_scan1(const int* __restrict__ cnt,
                                               int* __restrict__ offs,
                                               int* __restrict__ bsum,
                                               float* __restrict__ dinv) {
  __shared__ int s[256];
  int t = threadIdx.x;
  int i = blockIdx.x * 256 + t;
  int v = (i < N_NODES) ? cnt[i] : 0;
  s[t] = v;
  __syncthreads();
  for (int o = 1; o < 256; o <<= 1) {
    int add = (t >= o) ? s[t - o] : 0;
    __syncthreads();
    s[t] += add;
    __syncthreads();
  }
  if (i < N_NODES) {
    offs[i] = s[t] - v;                    // block-local exclusive
    dinv[i] = rsqrtf((float)v + 1.0f);     // +1 self loop
  }
  if (t == 255) bsum[blockIdx.x] = s[255];
}

// serial scan of 391 block sums (trivial)
__global__ void k_scan2(int* __restrict__ bsum) {
  if (threadIdx.x == 0 && blockIdx.x == 0) {
    int acc = 0;
    for (int i = 0; i < NBN; ++i) { int v = bsum[i]; bsum[i] = acc; acc += v; }
  }
}

// ---------------- CSR fill: csr[slot(dst)] = src ----------------
__global__ __launch_bounds__(256) void k_fill(const int* __restrict__ ei,
                                              const int* __restrict__ offs,
                                              const int* __restrict__ bsum,
                                              int* __restrict__ cursor,
                                              int* __restrict__ csr) {
  int e = blockIdx.x * 256 + threadIdx.x;
  if (e < N_EDGES) {
    int s = ei[e];
    int d = ei[N_EDGES + e];
    int pos = offs[d] + bsum[d >> 8] + atomicAdd(&cursor[d], 1);
    csr[pos] = s;
  }
}

// ---------------- GEMM1: t1 = X @ W1 ----------------
__global__ __launch_bounds__(128) void k_gemm1(const float* __restrict__ X,
                                               const float* __restrict__ W,
                                               float* __restrict__ T1) {
  __shared__ float Ws[64 * 16];        // 4 KB
  __shared__ float Xs[2][64 * 65];     // 33.3 KB
  const int wave = threadIdx.x >> 6;
  const int lane = threadIdx.x & 63;
  const int rowBase = blockIdx.x * 128 + wave * 64;
  const int myRow = rowBase + lane;

  float acc[16];
#pragma unroll
  for (int j = 0; j < 16; ++j) acc[j] = 0.f;

  for (int kt = 0; kt < F_INN; kt += 64) {
    {
      int t = threadIdx.x;
      float4 w0 = *(const float4*)(W + kt * 16 + t * 8);
      float4 w1 = *(const float4*)(W + kt * 16 + t * 8 + 4);
      *(float4*)(&Ws[t * 8]) = w0;
      *(float4*)(&Ws[t * 8 + 4]) = w1;
    }
#pragma unroll
    for (int i = 0; i < 16; ++i) {
      int f = i * 64 + lane;
      int r = f >> 4;
      int kq = f & 15;
      int gr = rowBase + r;
      float4 v = make_float4(0.f, 0.f, 0.f, 0.f);
      if (gr < N_NODES) v = *(const float4*)(X + (size_t)gr * F_INN + kt + kq * 4);
      float* p = &Xs[wave][r * 65 + kq * 4];
      p[0] = v.x; p[1] = v.y; p[2] = v.z; p[3] = v.w;
    }
    __syncthreads();
#pragma unroll 8
    for (int k = 0; k < 64; ++k) {
      float xv = Xs[wave][lane * 65 + k];
#pragma unroll
      for (int j = 0; j < 16; ++j) acc[j] = fmaf(xv, Ws[k * 16 + j], acc[j]);
    }
    __syncthreads();
  }

  if (myRow < N_NODES) {
    float4* t = (float4*)(T1 + (size_t)myRow * 16);
#pragma unroll
    for (int q = 0; q < 4; ++q)
      t[q] = make_float4(acc[q * 4 + 0], acc[q * 4 + 1], acc[q * 4 + 2], acc[q * 4 + 3]);
  }
}

// ---------------- gather layer 1: o1[d] = dinv[d]^2*t1[d] + sum_e dinv[s]dinv[d] t1[s] ----------------
// 4 threads per node, one float4 quarter each
__global__ __launch_bounds__(256) void k_gather1(const int* __restrict__ csr,
                                                 const int* __restrict__ offs,
                                                 const int* __restrict__ bsum,
                                                 const int* __restrict__ cnt,
                                                 const float* __restrict__ dinv,
                                                 const float* __restrict__ T1,
                                                 float* __restrict__ O1) {
  int node = blockIdx.x * 64 + (threadIdx.x >> 2);
  int q = threadIdx.x & 3;
  if (node >= N_NODES) return;
  float dd = dinv[node];
  int start = offs[node] + bsum[node >> 8];
  int len = cnt[node];
  float4 v = *(const float4*)(T1 + (size_t)node * 16 + q * 4);
  float w0 = dd * dd;
  float4 acc = make_float4(w0 * v.x, w0 * v.y, w0 * v.z, w0 * v.w);
  for (int i = 0; i < len; ++i) {
    int s = csr[start + i];
    float w = dinv[s] * dd;
    float4 u = *(const float4*)(T1 + (size_t)s * 16 + q * 4);
    acc.x = fmaf(w, u.x, acc.x);
    acc.y = fmaf(w, u.y, acc.y);
    acc.z = fmaf(w, u.z, acc.z);
    acc.w = fmaf(w, u.w, acc.w);
  }
  *(float4*)(O1 + (size_t)node * 16 + q * 4) = acc;
}

// ---------------- layer 2: h = relu(o1 + b1); t2 = h @ W2 ----------------
__global__ __launch_bounds__(256) void k_l2(const float* __restrict__ O1,
                                            const float* __restrict__ b1,
                                            const float* __restrict__ W2,
                                            float* __restrict__ T2) {
  int i = blockIdx.x * 256 + threadIdx.x;
  if (i >= N_NODES) return;
  const float4* r4 = (const float4*)(O1 + (size_t)i * 16);
  float a0 = 0.f, a1 = 0.f;
#pragma unroll
  for (int q = 0; q < 4; ++q) {
    float4 v = r4[q];
    float h0 = fmaxf(v.x + b1[q * 4 + 0], 0.f);
    float h1 = fmaxf(v.y + b1[q * 4 + 1], 0.f);
    float h2 = fmaxf(v.z + b1[q * 4 + 2], 0.f);
    float h3 = fmaxf(v.w + b1[q * 4 + 3], 0.f);
    a0 = fmaf(h0, W2[(q * 4 + 0) * 2], fmaf(h1, W2[(q * 4 + 1) * 2], fmaf(h2, W2[(q * 4 + 2) * 2], fmaf(h3, W2[(q * 4 + 3) * 2], a0))));
    a1 = fmaf(h0, W2[(q * 4 + 0) * 2 + 1], fmaf(h1, W2[(q * 4 + 1) * 2 + 1], fmaf(h2, W2[(q * 4 + 2) * 2 + 1], fmaf(h3, W2[(q * 4 + 3) * 2 + 1], a1))));
  }
  T2[i * 2 + 0] = a0;
  T2[i * 2 + 1] = a1;
}

// ---------------- gather layer 2 ----------------
__global__ __launch_bounds__(256) void k_gather2(const int* __restrict__ csr,
                                                 const int* __restrict__ offs,
                                                 const int* __restrict__ bsum,
                                                 const int* __restrict__ cnt,
                                                 const float* __restrict__ dinv,
                                                 const float* __restrict__ T2,
                                                 float* __restrict__ O2) {
  int node = blockIdx.x * 256 + threadIdx.x;
  if (node >= N_NODES) return;
  float dd = dinv[node];
  int start = offs[node] + bsum[node >> 8];
  int len = cnt[node];
  float2 v = *(const float2*)(T2 + (size_t)node * 2);
  float w0 = dd * dd;
  float ax = w0 * v.x, ay = w0 * v.y;
  for (int i = 0; i < len; ++i) {
    int s = csr[start + i];
    float w = dinv[s] * dd;
    float2 u = *(const float2*)(T2 + (size_t)s * 2);
    ax = fmaf(w, u.x, ax);
    ay = fmaf(w, u.y, ay);
  }
  O2[node * 2 + 0] = ax;
  O2[node * 2 + 1] = ay;
}

// ---------------- pooling ----------------
__global__ __launch_bounds__(256) void k_pool(const float* __restrict__ O2,
                                              const int* __restrict__ batch,
                                              float* __restrict__ pool,
                                              float* __restrict__ gcnt) {
  int i = blockIdx.x * 256 + threadIdx.x;
  bool valid = i < N_NODES;
  int b = valid ? batch[i] : -1;
  float vx = 0.f, vy = 0.f;
  if (valid) {
    vx = O2[(size_t)i * 2 + 0];
    vy = O2[(size_t)i * 2 + 1];
  }
  int b0 = __shfl(b, 0);
  if (__all(b == b0)) {
    if (b0 >= 0) {
#pragma unroll
      for (int o = 32; o > 0; o >>= 1) {
        vx += __shfl_xor(vx, o);
        vy += __shfl_xor(vy, o);
      }
      if ((threadIdx.x & 63) == 0) {
        atomicAdd(&pool[b0 * 2 + 0], vx);
        atomicAdd(&pool[b0 * 2 + 1], vy);
        atomicAdd(&gcnt[b0], 64.0f);
      }
    }
  } else if (valid) {
    atomicAdd(&pool[b * 2 + 0], vx);
    atomicAdd(&pool[b * 2 + 1], vy);
    atomicAdd(&gcnt[b], 1.0f);
  }
}

// ---------------- final ----------------
__global__ __launch_bounds__(256) void k_final(const float* __restrict__ pool,
                                               const float* __restrict__ gcnt,
                                               const float* __restrict__ b2,
                                               float* __restrict__ out) {
  int g = threadIdx.x;
  if (g < NGR) {
    float c = fmaxf(gcnt[g], 1.0f);
    float p0 = pool[g * 2 + 0] / c + b2[0];
    float p1 = pool[g * 2 + 1] / c + b2[1];
    float m = fmaxf(p0, p1);
    float l = logf(expf(p0 - m) + expf(p1 - m));
    out[g * 2 + 0] = p0 - m - l;
    out[g * 2 + 1] = p1 - m - l;
  }
}

extern "C" void kernel_launch(void* const* d_in, const int* in_sizes, int n_in,
                              void* d_out, int out_size, void* d_ws, size_t ws_size,
                              hipStream_t stream) {
  const float* x  = (const float*)d_in[0];
  const float* W1 = (const float*)d_in[1];
  const float* b1 = (const float*)d_in[2];
  const float* W2 = (const float*)d_in[3];
  const float* b2 = (const float*)d_in[4];
  const int*   ei = (const int*)d_in[5];
  const int*   bt = (const int*)d_in[6];
  float* out = (float*)d_out;

  char* ws = (char*)d_ws;
  float* dinv   = (float*)ws;                 ws += (size_t)N_NODES * 4;
  int*   cnt    = (int*)ws;                   ws += (size_t)N_NODES * 4;
  int*   offs   = (int*)ws;                   ws += (size_t)N_NODES * 4;
  int*   bsum   = (int*)ws;                   ws += 512 * 4;
  int*   cursor = (int*)ws;                   ws += (size_t)N_NODES * 4;
  int*   csr    = (int*)ws;                   ws += (size_t)N_EDGES * 4;
  float* t1     = (float*)ws;                 ws += (size_t)N_NODES * 16 * 4;
  float* o1     = (float*)ws;                 ws += (size_t)N_NODES * 16 * 4;
  float* pool   = (float*)ws;                 ws += 2 * NGR * 4;
  float* gcnt   = (float*)ws;                 ws += NGR * 4;
  // t2/o2 alias t1 (t1 is dead after k_gather1)
  float* t2 = t1;
  float* o2 = t1 + (size_t)N_NODES * 2;

  hipMemsetAsync(cnt, 0, (size_t)N_NODES * 4, stream);
  hipMemsetAsync(cursor, 0, (size_t)N_NODES * 4, stream);
  hipMemsetAsync(pool, 0, (size_t)(3 * NGR) * 4, stream);

  k_deg  <<<N_EDGES / 256, 256, 0, stream>>>(ei, cnt);
  k_scan1<<<NBN, 256, 0, stream>>>(cnt, offs, bsum, dinv);
  k_scan2<<<1, 64, 0, stream>>>(bsum);
  k_fill <<<N_EDGES / 256, 256, 0, stream>>>(ei, offs, bsum, cursor, csr);
  k_gemm1<<<(N_NODES + 127) / 128, 128, 0, stream>>>(x, W1, t1);
  k_gather1<<<(N_NODES + 63) / 64, 256, 0, stream>>>(csr, offs, bsum, cnt, dinv, t1, o1);
  k_l2   <<<NBN, 256, 0, stream>>>(o1, b1, W2, t2);
  k_gather2<<<NBN, 256, 0, stream>>>(csr, offs, bsum, cnt, dinv, t2, o2);
  k_pool <<<NBN, 256, 0, stream>>>(o2, bt, pool, gcnt);
  k_final<<<1, 256, 0, stream>>>(pool, gcnt, b2, out);
}